// Round 3
// baseline (1016.688 us; speedup 1.0000x reference)
//
#include <hip/hip_runtime.h>
#include <hip/hip_bf16.h>
#include <stdint.h>

// BitSwarmLinear: out = x @ sign(population.sum(axis=2))^T
//   x:          (4, 4096, 2048) fp32  -> A, M=16384, K=2048
//   population: (2048, 2048, 32) fp32 -> reduced+signed -> W (N=2048, K=2048), ±1
//   out:        (4, 4096, 2048) fp32  -> C, M x N
//
// R3: R1 structure (inline fp32->bf16 A staging — the cvt_x prepass was a net
// loss, x moved 3x instead of 1x) + BK=64 (32 KiB LDS, occupancy preserved at
// 3 blocks/CU, barrier drains halved vs BK=32).

static constexpr int M_DIM = 16384;
static constexpr int N_DIM = 2048;
static constexpr int K_DIM = 2048;

typedef __attribute__((ext_vector_type(8))) short short8;   // 8 x bf16 = 4 VGPRs
typedef __attribute__((ext_vector_type(4))) float f32x4;    // MFMA accumulator

// fp32 -> bf16 round-to-nearest-even (no NaN inputs here)
__device__ __forceinline__ ushort f2bf(float f) {
    uint32_t u = __float_as_uint(f);
    u += 0x7FFFu + ((u >> 16) & 1u);
    return (ushort)(u >> 16);
}

// ---------------------------------------------------------------------------
// Kernel 1: swarm reduction + sign binarization. population is (N, K, 32)
// swarm-innermost: 8 lanes per output, float4 loads, 3 xor-shuffles.
// sign(0) -> +1  ==>  (s >= 0) ? +1 : -1.  512 MiB read => ~85 us HBM floor.
// ---------------------------------------------------------------------------
__global__ __launch_bounds__(256) void swarm_reduce(const float4* __restrict__ pop4,
                                                    ushort* __restrict__ W) {
    const int tid = blockIdx.x * 256 + threadIdx.x;
    float4 v = pop4[tid];
    float s = v.x + v.y + v.z + v.w;
    s += __shfl_xor(s, 1);
    s += __shfl_xor(s, 2);
    s += __shfl_xor(s, 4);
    if ((threadIdx.x & 7) == 0)
        W[tid >> 3] = (s >= 0.0f) ? (ushort)0x3F80 : (ushort)0xBF80;  // ±1.0 bf16
}

// ---------------------------------------------------------------------------
// Kernel 2: bf16 MFMA GEMM, C[m,n] = sum_k A[m,k] * W[n,k]  (B^T layout).
// 128x128 tile, BK=64 (2 k-steps of 32), 4 waves 2x2, each wave 4x4 MFMAs of
// 16x16x32 per k-step.
//   - W tile (bf16): global_load_lds width=16, contiguous layout (async DMA,
//     issued FIRST so it overlaps the A-side VALU conversion work).
//   - A tile (fp32 source): float4 load -> inline bf16 cvt -> 8 B LDS store.
// Fragment layouts (HW-verified, guide §3):
//   A[m = lane&15][k = 8*(lane>>4) + j]   B[k][n] == W[n][k] row-major
//   D[i = 4*(lane>>4) + r][j = lane&15]
// ---------------------------------------------------------------------------
#define BM 128
#define BN 128
#define BK 64

__global__ __launch_bounds__(256) void gemm_bt(const float* __restrict__ A,
                                               const ushort* __restrict__ B,
                                               float* __restrict__ C) {
    __shared__ ushort la[BM * BK];   // 16 KiB, A tile bf16, row-major [128][64]
    __shared__ ushort lb[BN * BK];   // 16 KiB, W tile,      row-major [128][64]

    const int t    = threadIdx.x;
    const int bm   = blockIdx.x;
    const int bn   = blockIdx.y;
    const int wave = t >> 6;
    const int lane = t & 63;
    const int wm   = (wave >> 1) * 64;
    const int wn   = (wave & 1) * 64;
    const int l16  = lane & 15;
    const int quad = lane >> 4;

    f32x4 acc[4][4];
    #pragma unroll
    for (int i = 0; i < 4; ++i)
        #pragma unroll
        for (int j = 0; j < 4; ++j)
            acc[i][j] = (f32x4){0.f, 0.f, 0.f, 0.f};

    const float*  Abase = A + (size_t)(bm * BM) * K_DIM;
    const ushort* Bbase = B + (size_t)(bn * BN) * K_DIM;

    for (int k0 = 0; k0 < K_DIM; k0 += BK) {
        // ---- W tile: 1024 16-byte chunks, 4 per thread, async DMA first ----
        #pragma unroll
        for (int i = 0; i < 4; ++i) {
            const int c   = i * 256 + t;
            const int row = c >> 3;              // 8 chunks per 128 B row
            const int kc  = (c & 7) * 8;
            __builtin_amdgcn_global_load_lds(
                (const __attribute__((address_space(1))) void*)(Bbase + (size_t)row * K_DIM + k0 + kc),
                (__attribute__((address_space(3))) void*)(&lb[c * 8]), 16, 0, 0);
        }
        // ---- A tile: fp32 float4 load -> bf16 cvt -> LDS (8 B store) ----
        #pragma unroll
        for (int i = 0; i < 8; ++i) {
            const int c   = i * 256 + t;         // float4 chunk id, 2048 total
            const int row = c >> 4;              // 16 float4 per 64-float row
            const int kc  = (c & 15) * 4;
            float4 v = *(const float4*)(Abase + (size_t)row * K_DIM + k0 + kc);
            union { uint2 u2; ushort s[4]; } pk;
            pk.s[0] = f2bf(v.x);
            pk.s[1] = f2bf(v.y);
            pk.s[2] = f2bf(v.z);
            pk.s[3] = f2bf(v.w);
            *(uint2*)(&la[row * BK + kc]) = pk.u2;
        }
        __syncthreads();

        // ---- 2 k-steps x 16 MFMAs; fragments loaded per step (VGPR flat) ----
        #pragma unroll
        for (int ks = 0; ks < 2; ++ks) {
            const int kb = ks * 32 + quad * 8;
            short8 af[4], bf[4];
            #pragma unroll
            for (int tm = 0; tm < 4; ++tm)
                af[tm] = *(const short8*)(&la[(wm + tm * 16 + l16) * BK + kb]);
            #pragma unroll
            for (int tn = 0; tn < 4; ++tn)
                bf[tn] = *(const short8*)(&lb[(wn + tn * 16 + l16) * BK + kb]);
            #pragma unroll
            for (int tm = 0; tm < 4; ++tm)
                #pragma unroll
                for (int tn = 0; tn < 4; ++tn)
                    acc[tm][tn] = __builtin_amdgcn_mfma_f32_16x16x32_bf16(
                        af[tm], bf[tn], acc[tm][tn], 0, 0, 0);
        }
        __syncthreads();
    }

    // ---- epilogue: D[i = 4*quad + r][j = l16] ----
    #pragma unroll
    for (int tm = 0; tm < 4; ++tm) {
        #pragma unroll
        for (int tn = 0; tn < 4; ++tn) {
            const int row0 = bm * BM + wm + tm * 16 + quad * 4;
            const int col  = bn * BN + wn + tn * 16 + l16;
            #pragma unroll
            for (int r = 0; r < 4; ++r)
                C[(size_t)(row0 + r) * N_DIM + col] = acc[tm][tn][r];
        }
    }
}

extern "C" void kernel_launch(void* const* d_in, const int* in_sizes, int n_in,
                              void* d_out, int out_size, void* d_ws, size_t ws_size,
                              hipStream_t stream) {
    const float* x   = (const float*)d_in[0];   // (4,4096,2048) fp32
    const float* pop = (const float*)d_in[1];   // (2048,2048,32) fp32
    float* out = (float*)d_out;
    ushort* W = (ushort*)d_ws;                  // 8 MiB: W bf16 (N,K)

    // Phase 1: reduce population -> W (±1 bf16). 2048*2048*32/4 float4s.
    swarm_reduce<<<(N_DIM * K_DIM * 8) / 256, 256, 0, stream>>>((const float4*)pop, W);

    // Phase 2: C = x @ W^T via bf16 MFMA (inline A conversion).
    dim3 grid(M_DIM / BM, N_DIM / BN);   // 128 x 16 = 2048 blocks
    gemm_bt<<<grid, 256, 0, stream>>>(x, W, out);
}